// Round 1
// baseline (400.097 us; speedup 1.0000x reference)
//
#include <hip/hip_runtime.h>

// Fused transformer block on MI355X (gfx950).
// Pipeline:
//   1. cast weights fp32->bf16 (3 small launches)
//   2. ln1: h = LN(x,g1,b1) -> bf16
//   3. gemm<0>: logits = h @ w_attn^T (fp32 out)
//   4. smres_ln: xres = x + softmax(mask ? logits : -1e9)  [in-place over logits buf]
//               h2 = LN(xres,g2,b2) -> bf16                [reuses h buffer]
//   5. gemm<1>: u = h2 @ w_fc^T + b_fc -> bf16
//   6. gemm<2>: out = xres + relu(u @ w_proj^T + b_proj) -> fp32 d_out
//
// GEMM: m97 structure — 128x128 tile, BK=32, 4 waves (2x2 of 64x64),
// global_load_lds width=16 staging, mfma_f32_16x16x32_bf16,
// C/D layout col=lane&15, row=(lane>>4)*4+reg (HW-verified mapping).

typedef __attribute__((ext_vector_type(8))) short short8;
typedef __attribute__((ext_vector_type(4))) short short4v;
typedef __attribute__((ext_vector_type(4))) float float4v;
typedef __attribute__((ext_vector_type(4))) int   int4v;

#define LN_EPS 1e-5f

__device__ __forceinline__ short f2bf(float f) {
  // round-to-nearest-even fp32 -> bf16 (finite inputs only)
  unsigned u = __float_as_uint(f);
  unsigned r = (u + 0x7fffu + ((u >> 16) & 1u)) >> 16;
  return (short)r;
}

// ---- block reduces for 192-thread (3-wave) row kernels ----
__device__ __forceinline__ float brsum192(float v, float* red) {
  #pragma unroll
  for (int o = 32; o > 0; o >>= 1) v += __shfl_down(v, o, 64);
  __syncthreads();                       // protect red[] reuse across calls
  if ((threadIdx.x & 63) == 0) red[threadIdx.x >> 6] = v;
  __syncthreads();
  return red[0] + red[1] + red[2];
}

__device__ __forceinline__ float brmax192(float v, float* red) {
  #pragma unroll
  for (int o = 32; o > 0; o >>= 1) v = fmaxf(v, __shfl_down(v, o, 64));
  __syncthreads();
  if ((threadIdx.x & 63) == 0) red[threadIdx.x >> 6] = v;
  __syncthreads();
  return fmaxf(fmaxf(red[0], red[1]), red[2]);
}

// ---- fp32 -> bf16 cast (weights) ----
__global__ void cast_bf16_kernel(const float* __restrict__ in, short* __restrict__ out, int n4) {
  int i = blockIdx.x * blockDim.x + threadIdx.x;
  if (i >= n4) return;
  float4v v = reinterpret_cast<const float4v*>(in)[i];
  short4v o;
  o.x = f2bf(v.x); o.y = f2bf(v.y); o.z = f2bf(v.z); o.w = f2bf(v.w);
  reinterpret_cast<short4v*>(out)[i] = o;
}

// ---- LN over rows of 768, write bf16 ----
__global__ __launch_bounds__(192) void ln_kernel(const float* __restrict__ x,
    const float* __restrict__ g, const float* __restrict__ b, short* __restrict__ h) {
  __shared__ float red[3];
  const int row = blockIdx.x, tid = threadIdx.x;
  const float4v v = reinterpret_cast<const float4v*>(x + (size_t)row * 768)[tid];
  const float s = brsum192(v.x + v.y + v.z + v.w, red);
  const float mu = s * (1.f / 768.f);
  const float dx = v.x - mu, dy = v.y - mu, dz = v.z - mu, dw = v.w - mu;
  const float sq = brsum192(dx*dx + dy*dy + dz*dz + dw*dw, red);
  const float rs = rsqrtf(sq * (1.f / 768.f) + LN_EPS);
  const float4v gv = reinterpret_cast<const float4v*>(g)[tid];
  const float4v bv = reinterpret_cast<const float4v*>(b)[tid];
  short4v o;
  o.x = f2bf(dx * rs * gv.x + bv.x);
  o.y = f2bf(dy * rs * gv.y + bv.y);
  o.z = f2bf(dz * rs * gv.z + bv.z);
  o.w = f2bf(dw * rs * gv.w + bv.w);
  reinterpret_cast<short4v*>(h + (size_t)row * 768)[tid] = o;
}

// ---- masked softmax + residual + LN2 (+bf16 cast), one row per block ----
__global__ __launch_bounds__(192) void smres_ln_kernel(
    float* __restrict__ lgx,            // in: logits, out: xres (in-place)
    const float* __restrict__ x, const int* __restrict__ mask,
    const float* __restrict__ g, const float* __restrict__ b,
    short* __restrict__ h2) {
  __shared__ float red[3];
  const int row = blockIdx.x, tid = threadIdx.x;
  const int srow = row & 4095;          // mask is [S,E], broadcast over batch
  const float4v lg = reinterpret_cast<float4v*>(lgx + (size_t)row * 768)[tid];
  const int4v mk = reinterpret_cast<const int4v*>(mask + (size_t)srow * 768)[tid];
  const float m0 = mk.x ? lg.x : -1e9f;
  const float m1 = mk.y ? lg.y : -1e9f;
  const float m2 = mk.z ? lg.z : -1e9f;
  const float m3 = mk.w ? lg.w : -1e9f;
  const float mx = brmax192(fmaxf(fmaxf(m0, m1), fmaxf(m2, m3)), red);
  const float p0 = __expf(m0 - mx), p1 = __expf(m1 - mx);
  const float p2 = __expf(m2 - mx), p3 = __expf(m3 - mx);
  const float inv = 1.f / brsum192(p0 + p1 + p2 + p3, red);
  const float4v xv = reinterpret_cast<const float4v*>(x + (size_t)row * 768)[tid];
  const float r0 = xv.x + p0 * inv, r1 = xv.y + p1 * inv;
  const float r2 = xv.z + p2 * inv, r3 = xv.w + p3 * inv;
  float4v xr; xr.x = r0; xr.y = r1; xr.z = r2; xr.w = r3;
  reinterpret_cast<float4v*>(lgx + (size_t)row * 768)[tid] = xr;
  const float mu = brsum192(r0 + r1 + r2 + r3, red) * (1.f / 768.f);
  const float d0 = r0 - mu, d1 = r1 - mu, d2 = r2 - mu, d3 = r3 - mu;
  const float var = brsum192(d0*d0 + d1*d1 + d2*d2 + d3*d3, red) * (1.f / 768.f);
  const float rs = rsqrtf(var + LN_EPS);
  const float4v gv = reinterpret_cast<const float4v*>(g)[tid];
  const float4v bv = reinterpret_cast<const float4v*>(b)[tid];
  short4v o;
  o.x = f2bf(d0 * rs * gv.x + bv.x);
  o.y = f2bf(d1 * rs * gv.y + bv.y);
  o.z = f2bf(d2 * rs * gv.z + bv.z);
  o.w = f2bf(d3 * rs * gv.w + bv.w);
  reinterpret_cast<short4v*>(h2 + (size_t)row * 768)[tid] = o;
}

// ---- bf16 MFMA GEMM: C[M,N] = A[M,K] @ B[N,K]^T, 128x128 tile, BK=32 ----
// EPI 0: store fp32          (logits)
// EPI 1: +bias, store bf16   (u)
// EPI 2: +bias, relu, +resid, store fp32 (final output)
template<int EPI>
__global__ __launch_bounds__(256) void gemm_bt(
    const short* __restrict__ A, const short* __restrict__ Bm,
    int N, int K,
    float* __restrict__ Cf, short* __restrict__ Cb,
    const float* __restrict__ bias, const float* __restrict__ resid) {
  __shared__ __align__(16) short smem[8192];   // A tile [128][32] @0, B tile [128][32] @4096
  const int tid  = threadIdx.x;
  const int lane = tid & 63;
  const int wid  = tid >> 6;
  const int bm = blockIdx.y, bn = blockIdx.x;
  const int wr = wid >> 1, wc = wid & 1;       // 2x2 waves of 64x64 output
  const int lr = lane & 15, kg = lane >> 4;
  const int srow = lane >> 2;                  // staging: row within 16-row chunk
  const int skq  = lane & 3;                   // staging: 8-elem K group

  float4v acc[4][4] = {};

  const int nk = K >> 5;
  for (int kt = 0; kt < nk; ++kt) {
    __syncthreads();                           // protect LDS from prior-iter reads
    const int kcol = (kt << 5) + skq * 8;
    #pragma unroll
    for (int i = 0; i < 4; ++i) {
      const int c = (wid << 2) + i;            // 16 wave-issues: 0-7 A rows, 8-15 B rows
      const short* src;
      if (c < 8) src = A  + (size_t)(bm * 128 + c * 16 + srow) * (size_t)K + kcol;
      else       src = Bm + (size_t)(bn * 128 + (c - 8) * 16 + srow) * (size_t)K + kcol;
      __builtin_amdgcn_global_load_lds(
          (const __attribute__((address_space(1))) void*)src,
          (__attribute__((address_space(3))) void*)((char*)smem + (c << 10) + lane * 16),
          16, 0, 0);
    }
    __syncthreads();                           // compiler drains vmcnt before barrier
    short8 a[4], b[4];
    #pragma unroll
    for (int m = 0; m < 4; ++m)
      a[m] = *(const short8*)&smem[((wr << 6) + (m << 4) + lr) * 32 + (kg << 3)];
    #pragma unroll
    for (int n = 0; n < 4; ++n)
      b[n] = *(const short8*)&smem[4096 + ((wc << 6) + (n << 4) + lr) * 32 + (kg << 3)];
    #pragma unroll
    for (int m = 0; m < 4; ++m)
      #pragma unroll
      for (int n = 0; n < 4; ++n)
        acc[m][n] = __builtin_amdgcn_mfma_f32_16x16x32_bf16(a[m], b[n], acc[m][n], 0, 0, 0);
  }

  const int rbase = bm * 128 + wr * 64;
  const int cbase = bn * 128 + wc * 64;
  #pragma unroll
  for (int m = 0; m < 4; ++m) {
    #pragma unroll
    for (int n = 0; n < 4; ++n) {
      const int c = cbase + n * 16 + lr;
      const float bv = (EPI >= 1) ? bias[c] : 0.f;
      #pragma unroll
      for (int j = 0; j < 4; ++j) {
        const int r = rbase + m * 16 + kg * 4 + j;
        float v = acc[m][n][j];
        if (EPI == 0) {
          Cf[(size_t)r * N + c] = v;
        } else if (EPI == 1) {
          Cb[(size_t)r * N + c] = f2bf(v + bv);
        } else {
          v = fmaxf(v + bv, 0.f) + resid[(size_t)r * N + c];
          Cf[(size_t)r * N + c] = v;
        }
      }
    }
  }
}

extern "C" void kernel_launch(void* const* d_in, const int* in_sizes, int n_in,
                              void* d_out, int out_size, void* d_ws, size_t ws_size,
                              hipStream_t stream) {
  const float* x      = (const float*)d_in[0];
  const float* g1     = (const float*)d_in[1];
  const float* b1     = (const float*)d_in[2];
  const float* w_attn = (const float*)d_in[3];
  const float* g2     = (const float*)d_in[4];
  const float* b2     = (const float*)d_in[5];
  const float* w_fc   = (const float*)d_in[6];
  const float* b_fc   = (const float*)d_in[7];
  const float* w_proj = (const float*)d_in[8];
  const float* b_proj = (const float*)d_in[9];
  const int*   mask   = (const int*)d_in[10];
  float* out = (float*)d_out;

  const int S = 4096, E = 768, H = 3072;
  const int M = 4 * S;                 // 16384 rows

  char* p = (char*)d_ws;
  short* hbuf = (short*)p; p += (size_t)M * E * 2;   // h, later reused as h2 (25.2 MB)
  float* lgx  = (float*)p; p += (size_t)M * E * 4;   // logits, later xres (50.3 MB)
  short* ubuf = (short*)p; p += (size_t)M * H * 2;   // u bf16 (100.7 MB)
  short* wa   = (short*)p; p += (size_t)E * E * 2;   // bf16 weights
  short* wf   = (short*)p; p += (size_t)H * E * 2;
  short* wp   = (short*)p; p += (size_t)E * H * 2;

  // 1. weight casts
  cast_bf16_kernel<<<(E*E/4 + 255)/256, 256, 0, stream>>>(w_attn, wa, E*E/4);
  cast_bf16_kernel<<<(H*E/4 + 255)/256, 256, 0, stream>>>(w_fc,   wf, H*E/4);
  cast_bf16_kernel<<<(E*H/4 + 255)/256, 256, 0, stream>>>(w_proj, wp, E*H/4);

  // 2. LN1
  ln_kernel<<<M, 192, 0, stream>>>(x, g1, b1, hbuf);

  // 3. logits = h @ w_attn^T
  gemm_bt<0><<<dim3(E/128, M/128), 256, 0, stream>>>(hbuf, wa, E, E, lgx, nullptr, nullptr, nullptr);

  // 4. masked softmax + residual + LN2
  smres_ln_kernel<<<M, 192, 0, stream>>>(lgx, x, mask, g2, b2, hbuf);

  // 5. u = h2 @ w_fc^T + b_fc  (bf16)
  gemm_bt<1><<<dim3(H/128, M/128), 256, 0, stream>>>(hbuf, wf, H, E, nullptr, ubuf, b_fc, nullptr);

  // 6. out = xres + relu(u @ w_proj^T + b_proj)
  gemm_bt<2><<<dim3(E/128, M/128), 256, 0, stream>>>(ubuf, wp, E, H, out, nullptr, b_proj, lgx);
}

// Round 2
// 352.728 us; speedup vs baseline: 1.1343x; 1.1343x over previous
//
#include <hip/hip_runtime.h>

// Fused transformer block on MI355X (gfx950).
// Pipeline:
//   1. cast weights fp32->bf16 (3 small launches)
//   2. ln1: h = LN(x,g1,b1) -> bf16
//   3. gemm<4,0>: logits = h @ w_attn^T (fp32 out)
//   4. smres_ln: xres = x + softmax(mask ? logits : -1e9)  [in-place]
//               h2 = LN(xres,g2,b2) -> bf16
//   5. gemm<4,1>: u = h2 @ w_fc^T + b_fc -> bf16
//   6. gemm<8,2>: out = xres + relu(u @ w_proj^T + b_proj) -> fp32 d_out
//
// GEMM: 128xBN tile (BN = NF*32), BK=32, 4 waves (2x2), 2-phase pipelined
// double-buffered LDS (STAGE next tile -> ds_read cur -> MFMA -> barrier),
// global_load_lds width=16 staging, mfma_f32_16x16x32_bf16.
// bm-major chunked XCD swizzle: blocks sharing an A-panel land on one XCD L2.

typedef __attribute__((ext_vector_type(8))) short short8;
typedef __attribute__((ext_vector_type(4))) short short4v;
typedef __attribute__((ext_vector_type(4))) float float4v;
typedef __attribute__((ext_vector_type(4))) int   int4v;

#define LN_EPS 1e-5f

__device__ __forceinline__ short f2bf(float f) {
  unsigned u = __float_as_uint(f);
  unsigned r = (u + 0x7fffu + ((u >> 16) & 1u)) >> 16;
  return (short)r;
}

// ---- block reduces for 192-thread (3-wave) row kernels ----
__device__ __forceinline__ float brsum192(float v, float* red) {
  #pragma unroll
  for (int o = 32; o > 0; o >>= 1) v += __shfl_down(v, o, 64);
  __syncthreads();
  if ((threadIdx.x & 63) == 0) red[threadIdx.x >> 6] = v;
  __syncthreads();
  return red[0] + red[1] + red[2];
}

__device__ __forceinline__ float brmax192(float v, float* red) {
  #pragma unroll
  for (int o = 32; o > 0; o >>= 1) v = fmaxf(v, __shfl_down(v, o, 64));
  __syncthreads();
  if ((threadIdx.x & 63) == 0) red[threadIdx.x >> 6] = v;
  __syncthreads();
  return fmaxf(fmaxf(red[0], red[1]), red[2]);
}

// ---- fp32 -> bf16 cast (weights) ----
__global__ void cast_bf16_kernel(const float* __restrict__ in, short* __restrict__ out, int n4) {
  int i = blockIdx.x * blockDim.x + threadIdx.x;
  if (i >= n4) return;
  float4v v = reinterpret_cast<const float4v*>(in)[i];
  short4v o;
  o.x = f2bf(v.x); o.y = f2bf(v.y); o.z = f2bf(v.z); o.w = f2bf(v.w);
  reinterpret_cast<short4v*>(out)[i] = o;
}

// ---- LN over rows of 768, write bf16 ----
__global__ __launch_bounds__(192) void ln_kernel(const float* __restrict__ x,
    const float* __restrict__ g, const float* __restrict__ b, short* __restrict__ h) {
  __shared__ float red[3];
  const int row = blockIdx.x, tid = threadIdx.x;
  const float4v v = reinterpret_cast<const float4v*>(x + (size_t)row * 768)[tid];
  const float s = brsum192(v.x + v.y + v.z + v.w, red);
  const float mu = s * (1.f / 768.f);
  const float dx = v.x - mu, dy = v.y - mu, dz = v.z - mu, dw = v.w - mu;
  const float sq = brsum192(dx*dx + dy*dy + dz*dz + dw*dw, red);
  const float rs = rsqrtf(sq * (1.f / 768.f) + LN_EPS);
  const float4v gv = reinterpret_cast<const float4v*>(g)[tid];
  const float4v bv = reinterpret_cast<const float4v*>(b)[tid];
  short4v o;
  o.x = f2bf(dx * rs * gv.x + bv.x);
  o.y = f2bf(dy * rs * gv.y + bv.y);
  o.z = f2bf(dz * rs * gv.z + bv.z);
  o.w = f2bf(dw * rs * gv.w + bv.w);
  reinterpret_cast<short4v*>(h + (size_t)row * 768)[tid] = o;
}

// ---- masked softmax + residual + LN2 (+bf16 cast), one row per block ----
__global__ __launch_bounds__(192) void smres_ln_kernel(
    float* __restrict__ lgx, const float* __restrict__ x, const int* __restrict__ mask,
    const float* __restrict__ g, const float* __restrict__ b, short* __restrict__ h2) {
  __shared__ float red[3];
  const int row = blockIdx.x, tid = threadIdx.x;
  const int srow = row & 4095;
  const float4v lg = reinterpret_cast<float4v*>(lgx + (size_t)row * 768)[tid];
  const int4v mk = reinterpret_cast<const int4v*>(mask + (size_t)srow * 768)[tid];
  const float m0 = mk.x ? lg.x : -1e9f;
  const float m1 = mk.y ? lg.y : -1e9f;
  const float m2 = mk.z ? lg.z : -1e9f;
  const float m3 = mk.w ? lg.w : -1e9f;
  const float mx = brmax192(fmaxf(fmaxf(m0, m1), fmaxf(m2, m3)), red);
  const float p0 = __expf(m0 - mx), p1 = __expf(m1 - mx);
  const float p2 = __expf(m2 - mx), p3 = __expf(m3 - mx);
  const float inv = 1.f / brsum192(p0 + p1 + p2 + p3, red);
  const float4v xv = reinterpret_cast<const float4v*>(x + (size_t)row * 768)[tid];
  const float r0 = xv.x + p0 * inv, r1 = xv.y + p1 * inv;
  const float r2 = xv.z + p2 * inv, r3 = xv.w + p3 * inv;
  float4v xr; xr.x = r0; xr.y = r1; xr.z = r2; xr.w = r3;
  reinterpret_cast<float4v*>(lgx + (size_t)row * 768)[tid] = xr;
  const float mu = brsum192(r0 + r1 + r2 + r3, red) * (1.f / 768.f);
  const float d0 = r0 - mu, d1 = r1 - mu, d2 = r2 - mu, d3 = r3 - mu;
  const float var = brsum192(d0*d0 + d1*d1 + d2*d2 + d3*d3, red) * (1.f / 768.f);
  const float rs = rsqrtf(var + LN_EPS);
  const float4v gv = reinterpret_cast<const float4v*>(g)[tid];
  const float4v bv = reinterpret_cast<const float4v*>(b)[tid];
  short4v o;
  o.x = f2bf(d0 * rs * gv.x + bv.x);
  o.y = f2bf(d1 * rs * gv.y + bv.y);
  o.z = f2bf(d2 * rs * gv.z + bv.z);
  o.w = f2bf(d3 * rs * gv.w + bv.w);
  reinterpret_cast<short4v*>(h2 + (size_t)row * 768)[tid] = o;
}

// ---- bf16 MFMA GEMM: C[M,N] = A[M,K] @ B[N,K]^T ----
// Tile 128 x (NF*32), BK=32, 4 waves as 2x2 (per-wave 64 x NF*16).
// 2-phase double-buffered pipeline; 1D grid, bm-major chunked XCD swizzle.
// EPI 0: store fp32; EPI 1: +bias store bf16; EPI 2: +bias relu +resid fp32.
template<int NF, int EPI>
__global__ __launch_bounds__(256) void gemm_bt(
    const short* __restrict__ A, const short* __restrict__ Bm,
    int N, int K, int NB,
    float* __restrict__ Cf, short* __restrict__ Cb,
    const float* __restrict__ bias, const float* __restrict__ resid) {
  constexpr int BN = NF * 32;                 // 128 or 256
  constexpr int CHUNKS = (128 + BN) / 16;     // 16-row x 32-col staging chunks
  constexpr int CPW = CHUNKS / 4;             // chunks per wave
  constexpr int BSH = (128 + BN) * 32;        // shorts per LDS buffer
  __shared__ __align__(16) short smem[2 * BSH];

  const int tid  = threadIdx.x;
  const int lane = tid & 63;
  const int wid  = tid >> 6;
  const int wr = wid >> 1, wc = wid & 1;
  const int lr = lane & 15, kg = lane >> 4;
  const int srow = lane >> 2;                 // staging row within chunk
  const int skq  = lane & 3;                  // staging 8-elem K group

  // bm-major chunked XCD swizzle (nwg divisible by 8 for all call sites)
  const int nwg = gridDim.x;
  const int cpx = nwg >> 3;
  const int bid = blockIdx.x;
  const int wid2 = (bid & 7) * cpx + (bid >> 3);
  const int bm = wid2 / NB, bn = wid2 - bm * NB;

  auto stage = [&](int buf, int kt) {
    const int kcol = (kt << 5) + skq * 8;
    #pragma unroll
    for (int i = 0; i < CPW; ++i) {
      const int c = wid * CPW + i;
      const short* src;
      if (c < 8) src = A  + (size_t)(bm * 128 + c * 16 + srow) * (size_t)K + kcol;
      else       src = Bm + (size_t)(bn * BN + (c - 8) * 16 + srow) * (size_t)K + kcol;
      __builtin_amdgcn_global_load_lds(
          (const __attribute__((address_space(1))) void*)src,
          (__attribute__((address_space(3))) void*)((char*)smem + buf * (BSH * 2) + (c << 10) + lane * 16),
          16, 0, 0);
    }
  };

  float4v acc[4][NF] = {};
  const int nk = K >> 5;

  stage(0, 0);
  __syncthreads();                            // drains vmcnt(0) before barrier

  int cur = 0;
  for (int kt = 0; kt < nk; ++kt) {
    if (kt + 1 < nk) stage(cur ^ 1, kt + 1);  // prefetch next K-tile
    short8 a[4], b[NF];
    const int ab = cur * BSH;
    #pragma unroll
    for (int m = 0; m < 4; ++m)
      a[m] = *(const short8*)&smem[ab + ((wr << 6) + (m << 4) + lr) * 32 + (kg << 3)];
    #pragma unroll
    for (int n = 0; n < NF; ++n)
      b[n] = *(const short8*)&smem[ab + 4096 + ((wc * (BN/2)) + (n << 4) + lr) * 32 + (kg << 3)];
    __builtin_amdgcn_s_setprio(1);
    #pragma unroll
    for (int m = 0; m < 4; ++m)
      #pragma unroll
      for (int n = 0; n < NF; ++n)
        acc[m][n] = __builtin_amdgcn_mfma_f32_16x16x32_bf16(a[m], b[n], acc[m][n], 0, 0, 0);
    __builtin_amdgcn_s_setprio(0);
    __syncthreads();                          // next tile staged & reads done
    cur ^= 1;
  }

  const int rbase = bm * 128 + wr * 64;
  const int cbase = bn * BN + wc * (BN / 2);
  #pragma unroll
  for (int m = 0; m < 4; ++m) {
    #pragma unroll
    for (int n = 0; n < NF; ++n) {
      const int c = cbase + n * 16 + lr;
      const float bv = (EPI >= 1) ? bias[c] : 0.f;
      #pragma unroll
      for (int j = 0; j < 4; ++j) {
        const int r = rbase + m * 16 + kg * 4 + j;
        float v = acc[m][n][j];
        if (EPI == 0) {
          Cf[(size_t)r * N + c] = v;
        } else if (EPI == 1) {
          Cb[(size_t)r * N + c] = f2bf(v + bv);
        } else {
          v = fmaxf(v + bv, 0.f) + resid[(size_t)r * N + c];
          Cf[(size_t)r * N + c] = v;
        }
      }
    }
  }
}

extern "C" void kernel_launch(void* const* d_in, const int* in_sizes, int n_in,
                              void* d_out, int out_size, void* d_ws, size_t ws_size,
                              hipStream_t stream) {
  const float* x      = (const float*)d_in[0];
  const float* g1     = (const float*)d_in[1];
  const float* b1     = (const float*)d_in[2];
  const float* w_attn = (const float*)d_in[3];
  const float* g2     = (const float*)d_in[4];
  const float* b2     = (const float*)d_in[5];
  const float* w_fc   = (const float*)d_in[6];
  const float* b_fc   = (const float*)d_in[7];
  const float* w_proj = (const float*)d_in[8];
  const float* b_proj = (const float*)d_in[9];
  const int*   mask   = (const int*)d_in[10];
  float* out = (float*)d_out;

  const int S = 4096, E = 768, H = 3072;
  const int M = 4 * S;                 // 16384 rows

  char* p = (char*)d_ws;
  short* hbuf = (short*)p; p += (size_t)M * E * 2;   // h / h2
  float* lgx  = (float*)p; p += (size_t)M * E * 4;   // logits / xres
  short* ubuf = (short*)p; p += (size_t)M * H * 2;   // u bf16
  short* wa   = (short*)p; p += (size_t)E * E * 2;
  short* wf   = (short*)p; p += (size_t)H * E * 2;
  short* wp   = (short*)p; p += (size_t)E * H * 2;

  // 1. weight casts
  cast_bf16_kernel<<<(E*E/4 + 255)/256, 256, 0, stream>>>(w_attn, wa, E*E/4);
  cast_bf16_kernel<<<(H*E/4 + 255)/256, 256, 0, stream>>>(w_fc,   wf, H*E/4);
  cast_bf16_kernel<<<(E*H/4 + 255)/256, 256, 0, stream>>>(w_proj, wp, E*H/4);

  // 2. LN1
  ln_kernel<<<M, 192, 0, stream>>>(x, g1, b1, hbuf);

  // 3. logits = h @ w_attn^T   (grid 6*128 = 768 blocks)
  gemm_bt<4,0><<<(E/128) * (M/128), 256, 0, stream>>>(hbuf, wa, E, E, E/128, lgx, nullptr, nullptr, nullptr);

  // 4. masked softmax + residual + LN2
  smres_ln_kernel<<<M, 192, 0, stream>>>(lgx, x, mask, g2, b2, hbuf);

  // 5. u = h2 @ w_fc^T + b_fc  (bf16)   (grid 24*128 = 3072 blocks)
  gemm_bt<4,1><<<(H/128) * (M/128), 256, 0, stream>>>(hbuf, wf, H, E, H/128, nullptr, ubuf, b_fc, nullptr);

  // 6. out = xres + relu(u @ w_proj^T + b_proj)   (BN=256, grid 3*128 = 384 blocks)
  gemm_bt<8,2><<<(E/256) * (M/128), 256, 0, stream>>>(ubuf, wp, E, H, E/256, out, nullptr, b_proj, lgx);
}

// Round 3
// 275.180 us; speedup vs baseline: 1.4539x; 1.2818x over previous
//
#include <hip/hip_runtime.h>

// Fused transformer block on MI355X (gfx950).
// GEMMs use the 256x256 8-phase template (m201/m204 lineage):
//   BM=BN=256, BK=64, 512 threads = 8 waves (2M x 4N), per-wave C = 128x64.
//   LDS 128 KiB = 2 buf x {A0,A1,B0,B1} halves, each 128x64 bf16 stored as
//   16x32 subtiles with st_16x32 swizzle (byte^=32 for subtile rows >= 8).
//   Stage via global_load_lds width=16, linear LDS dest + inverse-swizzled
//   global source (rule: both-sides-or-neither).
//   4 phases per K-tile: quadrants (0,0),(0,1),(1,1),(1,0); each phase:
//   ds_reads -> stage 1 half-tile -> s_barrier -> lgkmcnt(0) -> setprio(1)
//   -> 16 MFMA -> setprio(0) -> s_barrier.  vmcnt(6) once per K-tile
//   (3 half-tiles = 6 loads in flight), vmcnt(0) only at the tail.
//   Stage stream: tile t stages (t+1).B0 @p1, (t+2).A0 @p2, (t+2).B1 @p3,
//   (t+2).A1 @p4 -- each half's overwrite issues >=1 phase after its last
//   LDS read (WAR-safe via the phase-closing barrier).

typedef __attribute__((ext_vector_type(8))) short short8;
typedef __attribute__((ext_vector_type(4))) short short4v;
typedef __attribute__((ext_vector_type(4))) float float4v;
typedef __attribute__((ext_vector_type(4))) int   int4v;

#define LN_EPS 1e-5f

__device__ __forceinline__ short f2bf(float f) {
  unsigned u = __float_as_uint(f);
  unsigned r = (u + 0x7fffu + ((u >> 16) & 1u)) >> 16;
  return (short)r;
}

// ---- block reduces for 192-thread (3-wave) row kernels ----
__device__ __forceinline__ float brsum192(float v, float* red) {
  #pragma unroll
  for (int o = 32; o > 0; o >>= 1) v += __shfl_down(v, o, 64);
  __syncthreads();
  if ((threadIdx.x & 63) == 0) red[threadIdx.x >> 6] = v;
  __syncthreads();
  return red[0] + red[1] + red[2];
}

__device__ __forceinline__ float brmax192(float v, float* red) {
  #pragma unroll
  for (int o = 32; o > 0; o >>= 1) v = fmaxf(v, __shfl_down(v, o, 64));
  __syncthreads();
  if ((threadIdx.x & 63) == 0) red[threadIdx.x >> 6] = v;
  __syncthreads();
  return fmaxf(fmaxf(red[0], red[1]), red[2]);
}

// ---- fp32 -> bf16 cast (weights) ----
__global__ void cast_bf16_kernel(const float* __restrict__ in, short* __restrict__ out, int n4) {
  int i = blockIdx.x * blockDim.x + threadIdx.x;
  if (i >= n4) return;
  float4v v = reinterpret_cast<const float4v*>(in)[i];
  short4v o;
  o.x = f2bf(v.x); o.y = f2bf(v.y); o.z = f2bf(v.z); o.w = f2bf(v.w);
  reinterpret_cast<short4v*>(out)[i] = o;
}

// ---- LN over rows of 768, write bf16 ----
__global__ __launch_bounds__(192) void ln_kernel(const float* __restrict__ x,
    const float* __restrict__ g, const float* __restrict__ b, short* __restrict__ h) {
  __shared__ float red[3];
  const int row = blockIdx.x, tid = threadIdx.x;
  const float4v v = reinterpret_cast<const float4v*>(x + (size_t)row * 768)[tid];
  const float s = brsum192(v.x + v.y + v.z + v.w, red);
  const float mu = s * (1.f / 768.f);
  const float dx = v.x - mu, dy = v.y - mu, dz = v.z - mu, dw = v.w - mu;
  const float sq = brsum192(dx*dx + dy*dy + dz*dz + dw*dw, red);
  const float rs = rsqrtf(sq * (1.f / 768.f) + LN_EPS);
  const float4v gv = reinterpret_cast<const float4v*>(g)[tid];
  const float4v bv = reinterpret_cast<const float4v*>(b)[tid];
  short4v o;
  o.x = f2bf(dx * rs * gv.x + bv.x);
  o.y = f2bf(dy * rs * gv.y + bv.y);
  o.z = f2bf(dz * rs * gv.z + bv.z);
  o.w = f2bf(dw * rs * gv.w + bv.w);
  reinterpret_cast<short4v*>(h + (size_t)row * 768)[tid] = o;
}

// ---- masked softmax + residual + LN2 (+bf16 cast), one row per block ----
__global__ __launch_bounds__(192) void smres_ln_kernel(
    float* __restrict__ lgx, const float* __restrict__ x, const int* __restrict__ mask,
    const float* __restrict__ g, const float* __restrict__ b, short* __restrict__ h2) {
  __shared__ float red[3];
  const int row = blockIdx.x, tid = threadIdx.x;
  const int srow = row & 4095;
  const float4v lg = reinterpret_cast<float4v*>(lgx + (size_t)row * 768)[tid];
  const int4v mk = reinterpret_cast<const int4v*>(mask + (size_t)srow * 768)[tid];
  const float m0 = mk.x ? lg.x : -1e9f;
  const float m1 = mk.y ? lg.y : -1e9f;
  const float m2 = mk.z ? lg.z : -1e9f;
  const float m3 = mk.w ? lg.w : -1e9f;
  const float mx = brmax192(fmaxf(fmaxf(m0, m1), fmaxf(m2, m3)), red);
  const float p0 = __expf(m0 - mx), p1 = __expf(m1 - mx);
  const float p2 = __expf(m2 - mx), p3 = __expf(m3 - mx);
  const float inv = 1.f / brsum192(p0 + p1 + p2 + p3, red);
  const float4v xv = reinterpret_cast<const float4v*>(x + (size_t)row * 768)[tid];
  const float r0 = xv.x + p0 * inv, r1 = xv.y + p1 * inv;
  const float r2 = xv.z + p2 * inv, r3 = xv.w + p3 * inv;
  float4v xr; xr.x = r0; xr.y = r1; xr.z = r2; xr.w = r3;
  reinterpret_cast<float4v*>(lgx + (size_t)row * 768)[tid] = xr;
  const float mu = brsum192(r0 + r1 + r2 + r3, red) * (1.f / 768.f);
  const float d0 = r0 - mu, d1 = r1 - mu, d2 = r2 - mu, d3 = r3 - mu;
  const float var = brsum192(d0*d0 + d1*d1 + d2*d2 + d3*d3, red) * (1.f / 768.f);
  const float rs = rsqrtf(var + LN_EPS);
  const float4v gv = reinterpret_cast<const float4v*>(g)[tid];
  const float4v bv = reinterpret_cast<const float4v*>(b)[tid];
  short4v o;
  o.x = f2bf(d0 * rs * gv.x + bv.x);
  o.y = f2bf(d1 * rs * gv.y + bv.y);
  o.z = f2bf(d2 * rs * gv.z + bv.z);
  o.w = f2bf(d3 * rs * gv.w + bv.w);
  reinterpret_cast<short4v*>(h2 + (size_t)row * 768)[tid] = o;
}

// ---- 256x256 8-phase bf16 MFMA GEMM: C[M,N] = A[M,K] @ B[N,K]^T ----
// EPI 0: store fp32; EPI 1: +bias store bf16; EPI 2: +bias relu +resid fp32.
template<int EPI>
__global__ __launch_bounds__(512) void gemm256(
    const short* __restrict__ A, const short* __restrict__ Bm,
    int N, int K, int NB,
    float* __restrict__ Cf, short* __restrict__ Cb,
    const float* __restrict__ bias, const float* __restrict__ resid) {
  // 128 KiB LDS: buf (x2, 64 KiB) = A0,A1 @ 0,16K | B0,B1 @ 32K,48K (bytes)
  __shared__ __align__(16) short smem[65536];

  const int tid  = threadIdx.x;
  const int lane = tid & 63;
  const int wid  = tid >> 6;           // 0..7
  const int wm   = wid >> 2;           // 0..1  (64-row half within quadrant)
  const int wn   = wid & 3;            // 0..3  (32-col strip within quadrant)
  const int lr   = lane & 15, kg = lane >> 4;

  // XCD swizzle, bm-major (grid % 8 == 0 at all call sites)
  const int nwg = gridDim.x;
  const int cpx = nwg >> 3;
  const int bid = blockIdx.x;
  const int sw  = (bid & 7) * cpx + (bid >> 3);
  const int bm = sw / NB, bn = sw - bm * NB;

  const int nk = K >> 6;               // K-tiles of 64 (nk >= 3 at all call sites)

  // staging lane constants (inverse st_16x32 swizzle on the GLOBAL source)
  const int srl = lane >> 2;                                   // subtile row 0..15
  const int sce = ((lane & 3) << 3) ^ ((lane & 32) ? 16 : 0);  // col elems in 32-col subtile

  // stage one 128x64 half-tile: 16 subtiles of 1024 B, 2 global_load_lds per wave
  auto stageA = [&](int h, int kt, int bb) {
    const size_t row0 = (size_t)(bm * 256 + h * 128);
    #pragma unroll
    for (int i = 0; i < 2; ++i) {
      const int s = i * 8 + wid;
      const short* src = A + (row0 + (s >> 1) * 16 + srl) * (size_t)K + (kt << 6) + (s & 1) * 32 + sce;
      __builtin_amdgcn_global_load_lds(
        (const __attribute__((address_space(1))) void*)src,
        (__attribute__((address_space(3))) void*)((char*)smem + bb * 65536 + h * 16384 + s * 1024 + lane * 16),
        16, 0, 0);
    }
  };
  auto stageB = [&](int h, int kt, int bb) {
    const size_t row0 = (size_t)(bn * 256 + h * 128);
    #pragma unroll
    for (int i = 0; i < 2; ++i) {
      const int s = i * 8 + wid;
      const short* src = Bm + (row0 + (s >> 1) * 16 + srl) * (size_t)K + (kt << 6) + (s & 1) * 32 + sce;
      __builtin_amdgcn_global_load_lds(
        (const __attribute__((address_space(1))) void*)src,
        (__attribute__((address_space(3))) void*)((char*)smem + bb * 65536 + 32768 + h * 16384 + s * 1024 + lane * 16),
        16, 0, 0);
    }
  };

  // swizzled within-subtile read offset (shorts): row lr, 16B chunk kg
  const int rdoff = lr * 32 + ((kg << 3) ^ ((lr & 8) << 1));

  float4v acc[2][2][4][2] = {};   // [qa][qb][m][n]
  short8 a[4][2], b[2][2];        // [frag][ks]

  // ---- prologue: stage t0.{A0,B0,B1,A1} + t1.{A0,B1,A1}; keep 3 halves in flight
  stageA(0, 0, 0); stageB(0, 0, 0); stageB(1, 0, 0); stageA(1, 0, 0);
  stageA(0, 1, 1); stageB(1, 1, 1); stageA(1, 1, 1);
  asm volatile("s_waitcnt vmcnt(6)" ::: "memory");   // tile 0 fully landed
  __builtin_amdgcn_sched_barrier(0);
  __builtin_amdgcn_s_barrier();

  for (int t = 0; t < nk; ++t) {
    const int bb  = t & 1;
    const int ab  = bb * 32768;            // A halves base (shorts)
    const int bbb = bb * 32768 + 16384;    // B halves base (shorts)

    // ======== phase 1: quadrant (0,0) — read A0, B0; stage (t+1).B0 ========
    #pragma unroll
    for (int m = 0; m < 4; ++m)
      #pragma unroll
      for (int ks = 0; ks < 2; ++ks)
        a[m][ks] = *(const short8*)&smem[ab + (((wm * 4 + m) * 2 + ks) << 9) + rdoff];
    #pragma unroll
    for (int n = 0; n < 2; ++n)
      #pragma unroll
      for (int ks = 0; ks < 2; ++ks)
        b[n][ks] = *(const short8*)&smem[bbb + (((wn * 2 + n) * 2 + ks) << 9) + rdoff];
    if (t + 1 < nk) stageB(0, t + 1, bb ^ 1);
    __builtin_amdgcn_sched_barrier(0);
    __builtin_amdgcn_s_barrier();
    asm volatile("s_waitcnt lgkmcnt(0)" ::: "memory");
    __builtin_amdgcn_sched_barrier(0);
    __builtin_amdgcn_s_setprio(1);
    #pragma unroll
    for (int m = 0; m < 4; ++m)
      #pragma unroll
      for (int n = 0; n < 2; ++n)
        #pragma unroll
        for (int ks = 0; ks < 2; ++ks)
          acc[0][0][m][n] = __builtin_amdgcn_mfma_f32_16x16x32_bf16(a[m][ks], b[n][ks], acc[0][0][m][n], 0, 0, 0);
    __builtin_amdgcn_s_setprio(0);
    __builtin_amdgcn_sched_barrier(0);
    __builtin_amdgcn_s_barrier();

    // ======== phase 2: quadrant (0,1) — read B1 (A0 in regs); stage (t+2).A0 ========
    #pragma unroll
    for (int n = 0; n < 2; ++n)
      #pragma unroll
      for (int ks = 0; ks < 2; ++ks)
        b[n][ks] = *(const short8*)&smem[bbb + 8192 + (((wn * 2 + n) * 2 + ks) << 9) + rdoff];
    if (t + 2 < nk) stageA(0, t + 2, bb);
    __builtin_amdgcn_sched_barrier(0);
    __builtin_amdgcn_s_barrier();
    asm volatile("s_waitcnt lgkmcnt(0)" ::: "memory");
    __builtin_amdgcn_sched_barrier(0);
    __builtin_amdgcn_s_setprio(1);
    #pragma unroll
    for (int m = 0; m < 4; ++m)
      #pragma unroll
      for (int n = 0; n < 2; ++n)
        #pragma unroll
        for (int ks = 0; ks < 2; ++ks)
          acc[0][1][m][n] = __builtin_amdgcn_mfma_f32_16x16x32_bf16(a[m][ks], b[n][ks], acc[0][1][m][n], 0, 0, 0);
    __builtin_amdgcn_s_setprio(0);
    __builtin_amdgcn_sched_barrier(0);
    __builtin_amdgcn_s_barrier();

    // ======== phase 3: quadrant (1,1) — read A1 (B1 in regs); stage (t+2).B1 ========
    #pragma unroll
    for (int m = 0; m < 4; ++m)
      #pragma unroll
      for (int ks = 0; ks < 2; ++ks)
        a[m][ks] = *(const short8*)&smem[ab + 8192 + (((wm * 4 + m) * 2 + ks) << 9) + rdoff];
    if (t + 2 < nk) stageB(1, t + 2, bb);
    __builtin_amdgcn_sched_barrier(0);
    __builtin_amdgcn_s_barrier();
    asm volatile("s_waitcnt lgkmcnt(0)" ::: "memory");
    __builtin_amdgcn_sched_barrier(0);
    __builtin_amdgcn_s_setprio(1);
    #pragma unroll
    for (int m = 0; m < 4; ++m)
      #pragma unroll
      for (int n = 0; n < 2; ++n)
        #pragma unroll
        for (int ks = 0; ks < 2; ++ks)
          acc[1][1][m][n] = __builtin_amdgcn_mfma_f32_16x16x32_bf16(a[m][ks], b[n][ks], acc[1][1][m][n], 0, 0, 0);
    __builtin_amdgcn_s_setprio(0);
    __builtin_amdgcn_sched_barrier(0);
    __builtin_amdgcn_s_barrier();

    // ======== phase 4: quadrant (1,0) — re-read B0 (A1 in regs); stage (t+2).A1 ========
    #pragma unroll
    for (int n = 0; n < 2; ++n)
      #pragma unroll
      for (int ks = 0; ks < 2; ++ks)
        b[n][ks] = *(const short8*)&smem[bbb + (((wn * 2 + n) * 2 + ks) << 9) + rdoff];
    if (t + 2 < nk) stageA(1, t + 2, bb);
    __builtin_amdgcn_sched_barrier(0);
    __builtin_amdgcn_s_barrier();
    asm volatile("s_waitcnt lgkmcnt(0)" ::: "memory");
    __builtin_amdgcn_sched_barrier(0);
    __builtin_amdgcn_s_setprio(1);
    #pragma unroll
    for (int m = 0; m < 4; ++m)
      #pragma unroll
      for (int n = 0; n < 2; ++n)
        #pragma unroll
        for (int ks = 0; ks < 2; ++ks)
          acc[1][0][m][n] = __builtin_amdgcn_mfma_f32_16x16x32_bf16(a[m][ks], b[n][ks], acc[1][0][m][n], 0, 0, 0);
    __builtin_amdgcn_s_setprio(0);
    __builtin_amdgcn_sched_barrier(0);
    __builtin_amdgcn_s_barrier();

    // ---- tile boundary: next tile's 4 halves landed; keep 3 halves in flight ----
    if (t + 2 < nk) { asm volatile("s_waitcnt vmcnt(6)" ::: "memory"); }
    else            { asm volatile("s_waitcnt vmcnt(0)" ::: "memory"); }
    __builtin_amdgcn_sched_barrier(0);
  }

  // ---- epilogue ----
  const int r0 = bm * 256 + wm * 64 + kg * 4;
  const int c0 = bn * 256 + wn * 32 + lr;
  #pragma unroll
  for (int qa = 0; qa < 2; ++qa) {
    #pragma unroll
    for (int qb = 0; qb < 2; ++qb) {
      #pragma unroll
      for (int n = 0; n < 2; ++n) {
        const int c = c0 + qb * 128 + n * 16;
        const float bv = (EPI >= 1) ? bias[c] : 0.f;
        #pragma unroll
        for (int m = 0; m < 4; ++m) {
          #pragma unroll
          for (int j = 0; j < 4; ++j) {
            const int r = r0 + qa * 128 + m * 16 + j;
            float v = acc[qa][qb][m][n][j];
            if (EPI == 0) {
              Cf[(size_t)r * N + c] = v;
            } else if (EPI == 1) {
              Cb[(size_t)r * N + c] = f2bf(v + bv);
            } else {
              v = fmaxf(v + bv, 0.f) + resid[(size_t)r * N + c];
              Cf[(size_t)r * N + c] = v;
            }
          }
        }
      }
    }
  }
}

extern "C" void kernel_launch(void* const* d_in, const int* in_sizes, int n_in,
                              void* d_out, int out_size, void* d_ws, size_t ws_size,
                              hipStream_t stream) {
  const float* x      = (const float*)d_in[0];
  const float* g1     = (const float*)d_in[1];
  const float* b1     = (const float*)d_in[2];
  const float* w_attn = (const float*)d_in[3];
  const float* g2     = (const float*)d_in[4];
  const float* b2     = (const float*)d_in[5];
  const float* w_fc   = (const float*)d_in[6];
  const float* b_fc   = (const float*)d_in[7];
  const float* w_proj = (const float*)d_in[8];
  const float* b_proj = (const float*)d_in[9];
  const int*   mask   = (const int*)d_in[10];
  float* out = (float*)d_out;

  const int S = 4096, E = 768, H = 3072;
  const int M = 4 * S;                 // 16384 rows

  char* p = (char*)d_ws;
  short* hbuf = (short*)p; p += (size_t)M * E * 2;   // h / h2
  float* lgx  = (float*)p; p += (size_t)M * E * 4;   // logits / xres
  short* ubuf = (short*)p; p += (size_t)M * H * 2;   // u bf16
  short* wa   = (short*)p; p += (size_t)E * E * 2;
  short* wf   = (short*)p; p += (size_t)H * E * 2;
  short* wp   = (short*)p; p += (size_t)E * H * 2;

  // 1. weight casts
  cast_bf16_kernel<<<(E*E/4 + 255)/256, 256, 0, stream>>>(w_attn, wa, E*E/4);
  cast_bf16_kernel<<<(H*E/4 + 255)/256, 256, 0, stream>>>(w_fc,   wf, H*E/4);
  cast_bf16_kernel<<<(E*H/4 + 255)/256, 256, 0, stream>>>(w_proj, wp, E*H/4);

  // 2. LN1
  ln_kernel<<<M, 192, 0, stream>>>(x, g1, b1, hbuf);

  // 3. logits = h @ w_attn^T   (grid 64*3 = 192)
  gemm256<0><<<(M/256) * (E/256), 512, 0, stream>>>(hbuf, wa, E, E, E/256, lgx, nullptr, nullptr, nullptr);

  // 4. masked softmax + residual + LN2
  smres_ln_kernel<<<M, 192, 0, stream>>>(lgx, x, mask, g2, b2, hbuf);

  // 5. u = h2 @ w_fc^T + b_fc  (bf16)   (grid 64*12 = 768)
  gemm256<1><<<(M/256) * (H/256), 512, 0, stream>>>(hbuf, wf, H, E, H/256, nullptr, ubuf, b_fc, nullptr);

  // 6. out = xres + relu(u @ w_proj^T + b_proj)   (grid 64*3 = 192)
  gemm256<2><<<(M/256) * (E/256), 512, 0, stream>>>(ubuf, wp, E, H, E/256, out, nullptr, b_proj, lgx);
}

// Round 5
// 249.068 us; speedup vs baseline: 1.6064x; 1.1048x over previous
//
#include <hip/hip_runtime.h>

// Fused transformer block on MI355X (gfx950).
// Two GEMM templates, both: BK=64, 512 thr = 8 waves, st_16x32-swizzled LDS
// (linear global_load_lds dest + inverse-swizzled global source), single
// barrier per phase (compiler emits counted lgkmcnt between ds_read and MFMA),
// counted vmcnt placed BEFORE the phase-closing barrier (per-wave certify,
// then publish), setprio(1) around MFMA clusters, bm-major XCD swizzle.
//
// gemm256: 256x256 tile, 4 quadrant-phases/K-tile, B0 kept in regs (p4 has
//          zero LDS reads). Stage stream: p1->(t+1).B0, p2->(t+2).A0,
//          p3->(t+2).B1, p4->(t+2).A1; boundary vmcnt(6).
//          LDS 128 KiB: buffer stride 65536 B (32768 shorts).
// gemm192: 256x192 tile (grid = 64*4 = 256 = exact CU cover for N=768),
//          2 phases/K-tile: p1 {read A0+B, stage (t+1).A0+A1, 24 MFMA},
//          p2 {read A1, stage (t+2).B, 24 MFMA, vmcnt(3)}.
//          LDS 112 KiB: buffer stride 57344 B (28672 shorts).  [R4 bug: used
//          114688 B / 57344 shorts -> OOB for buffer 1; fixed this round.]

typedef __attribute__((ext_vector_type(8))) short short8;
typedef __attribute__((ext_vector_type(4))) short short4v;
typedef __attribute__((ext_vector_type(4))) float float4v;
typedef __attribute__((ext_vector_type(4))) int   int4v;

#define LN_EPS 1e-5f

__device__ __forceinline__ short f2bf(float f) {
  unsigned u = __float_as_uint(f);
  unsigned r = (u + 0x7fffu + ((u >> 16) & 1u)) >> 16;
  return (short)r;
}

// ---- block reduces for 192-thread (3-wave) row kernels ----
__device__ __forceinline__ float brsum192(float v, float* red) {
  #pragma unroll
  for (int o = 32; o > 0; o >>= 1) v += __shfl_down(v, o, 64);
  __syncthreads();
  if ((threadIdx.x & 63) == 0) red[threadIdx.x >> 6] = v;
  __syncthreads();
  return red[0] + red[1] + red[2];
}

__device__ __forceinline__ float brmax192(float v, float* red) {
  #pragma unroll
  for (int o = 32; o > 0; o >>= 1) v = fmaxf(v, __shfl_down(v, o, 64));
  __syncthreads();
  if ((threadIdx.x & 63) == 0) red[threadIdx.x >> 6] = v;
  __syncthreads();
  return fmaxf(fmaxf(red[0], red[1]), red[2]);
}

// ---- fp32 -> bf16 cast (weights) ----
__global__ void cast_bf16_kernel(const float* __restrict__ in, short* __restrict__ out, int n4) {
  int i = blockIdx.x * blockDim.x + threadIdx.x;
  if (i >= n4) return;
  float4v v = reinterpret_cast<const float4v*>(in)[i];
  short4v o;
  o.x = f2bf(v.x); o.y = f2bf(v.y); o.z = f2bf(v.z); o.w = f2bf(v.w);
  reinterpret_cast<short4v*>(out)[i] = o;
}

// ---- LN over rows of 768, write bf16 ----
__global__ __launch_bounds__(192) void ln_kernel(const float* __restrict__ x,
    const float* __restrict__ g, const float* __restrict__ b, short* __restrict__ h) {
  __shared__ float red[3];
  const int row = blockIdx.x, tid = threadIdx.x;
  const float4v v = reinterpret_cast<const float4v*>(x + (size_t)row * 768)[tid];
  const float s = brsum192(v.x + v.y + v.z + v.w, red);
  const float mu = s * (1.f / 768.f);
  const float dx = v.x - mu, dy = v.y - mu, dz = v.z - mu, dw = v.w - mu;
  const float sq = brsum192(dx*dx + dy*dy + dz*dz + dw*dw, red);
  const float rs = rsqrtf(sq * (1.f / 768.f) + LN_EPS);
  const float4v gv = reinterpret_cast<const float4v*>(g)[tid];
  const float4v bv = reinterpret_cast<const float4v*>(b)[tid];
  short4v o;
  o.x = f2bf(dx * rs * gv.x + bv.x);
  o.y = f2bf(dy * rs * gv.y + bv.y);
  o.z = f2bf(dz * rs * gv.z + bv.z);
  o.w = f2bf(dw * rs * gv.w + bv.w);
  reinterpret_cast<short4v*>(h + (size_t)row * 768)[tid] = o;
}

// ---- masked softmax + residual + LN2 (+bf16 cast), one row per block ----
__global__ __launch_bounds__(192) void smres_ln_kernel(
    float* __restrict__ lgx, const float* __restrict__ x, const int* __restrict__ mask,
    const float* __restrict__ g, const float* __restrict__ b, short* __restrict__ h2) {
  __shared__ float red[3];
  const int row = blockIdx.x, tid = threadIdx.x;
  const int srow = row & 4095;
  const float4v lg = reinterpret_cast<float4v*>(lgx + (size_t)row * 768)[tid];
  const int4v mk = reinterpret_cast<const int4v*>(mask + (size_t)srow * 768)[tid];
  const float m0 = mk.x ? lg.x : -1e9f;
  const float m1 = mk.y ? lg.y : -1e9f;
  const float m2 = mk.z ? lg.z : -1e9f;
  const float m3 = mk.w ? lg.w : -1e9f;
  const float mx = brmax192(fmaxf(fmaxf(m0, m1), fmaxf(m2, m3)), red);
  const float p0 = __expf(m0 - mx), p1 = __expf(m1 - mx);
  const float p2 = __expf(m2 - mx), p3 = __expf(m3 - mx);
  const float inv = 1.f / brsum192(p0 + p1 + p2 + p3, red);
  const float4v xv = reinterpret_cast<const float4v*>(x + (size_t)row * 768)[tid];
  const float r0 = xv.x + p0 * inv, r1 = xv.y + p1 * inv;
  const float r2 = xv.z + p2 * inv, r3 = xv.w + p3 * inv;
  float4v xr; xr.x = r0; xr.y = r1; xr.z = r2; xr.w = r3;
  reinterpret_cast<float4v*>(lgx + (size_t)row * 768)[tid] = xr;
  const float mu = brsum192(r0 + r1 + r2 + r3, red) * (1.f / 768.f);
  const float d0 = r0 - mu, d1 = r1 - mu, d2 = r2 - mu, d3 = r3 - mu;
  const float var = brsum192(d0*d0 + d1*d1 + d2*d2 + d3*d3, red) * (1.f / 768.f);
  const float rs = rsqrtf(var + LN_EPS);
  const float4v gv = reinterpret_cast<const float4v*>(g)[tid];
  const float4v bv = reinterpret_cast<const float4v*>(b)[tid];
  short4v o;
  o.x = f2bf(d0 * rs * gv.x + bv.x);
  o.y = f2bf(d1 * rs * gv.y + bv.y);
  o.z = f2bf(d2 * rs * gv.z + bv.z);
  o.w = f2bf(d3 * rs * gv.w + bv.w);
  reinterpret_cast<short4v*>(h2 + (size_t)row * 768)[tid] = o;
}

// ================= gemm256: C[M,N] = A[M,K] @ B[N,K]^T, 256x256 =================
template<int EPI>
__global__ __launch_bounds__(512, 2) void gemm256(
    const short* __restrict__ A, const short* __restrict__ Bm,
    int N, int K, int NB,
    float* __restrict__ Cf, short* __restrict__ Cb,
    const float* __restrict__ bias, const float* __restrict__ resid) {
  // 128 KiB LDS: per buffer (64 KiB): A0@0, A1@16K, B0@32K, B1@48K (bytes)
  __shared__ __align__(16) short smem[65536];

  const int tid  = threadIdx.x;
  const int lane = tid & 63;
  const int wid  = tid >> 6;
  const int wm   = wid >> 2;           // 0..1
  const int wn   = wid & 3;            // 0..3
  const int lr   = lane & 15, kg = lane >> 4;

  const int nwg = gridDim.x;
  const int cpx = nwg >> 3;
  const int bid = blockIdx.x;
  const int sw  = (bid & 7) * cpx + (bid >> 3);
  const int bm = sw / NB, bn = sw - bm * NB;

  const int nk = K >> 6;

  const int srl = lane >> 2;
  const int sce = ((lane & 3) << 3) ^ ((lane & 32) ? 16 : 0);

  auto stageA = [&](int h, int kt, int bb) {
    const size_t row0 = (size_t)(bm * 256 + h * 128);
    #pragma unroll
    for (int i = 0; i < 2; ++i) {
      const int s = i * 8 + wid;
      const short* src = A + (row0 + (s >> 1) * 16 + srl) * (size_t)K + (kt << 6) + (s & 1) * 32 + sce;
      __builtin_amdgcn_global_load_lds(
        (const __attribute__((address_space(1))) void*)src,
        (__attribute__((address_space(3))) void*)((char*)smem + bb * 65536 + h * 16384 + s * 1024 + lane * 16),
        16, 0, 0);
    }
  };
  auto stageB = [&](int h, int kt, int bb) {
    const size_t row0 = (size_t)(bn * 256 + h * 128);
    #pragma unroll
    for (int i = 0; i < 2; ++i) {
      const int s = i * 8 + wid;
      const short* src = Bm + (row0 + (s >> 1) * 16 + srl) * (size_t)K + (kt << 6) + (s & 1) * 32 + sce;
      __builtin_amdgcn_global_load_lds(
        (const __attribute__((address_space(1))) void*)src,
        (__attribute__((address_space(3))) void*)((char*)smem + bb * 65536 + 32768 + h * 16384 + s * 1024 + lane * 16),
        16, 0, 0);
    }
  };

  const int rdoff = lr * 32 + ((kg << 3) ^ ((lr & 8) << 1));

  float4v acc[2][2][4][2] = {};   // [qa][qb][m][n]
  short8 a[4][2], b0[2][2], b1[2][2];

  // prologue: t0.{A0,B0,B1,A1} + t1.{A0,B1,A1}; certify t0, publish
  stageA(0, 0, 0); stageB(0, 0, 0); stageB(1, 0, 0); stageA(1, 0, 0);
  if (nk > 1) { stageA(0, 1, 1); stageB(1, 1, 1); stageA(1, 1, 1); }
  asm volatile("s_waitcnt vmcnt(6)" ::: "memory");
  __builtin_amdgcn_s_barrier();

  for (int t = 0; t < nk; ++t) {
    const int bb  = t & 1;
    const int ab  = bb * 32768;
    const int bbb = bb * 32768 + 16384;

    // p1: read A0 -> a, B0 -> b0; stage (t+1).B0; MFMA q(0,0)
    #pragma unroll
    for (int m = 0; m < 4; ++m)
      #pragma unroll
      for (int ks = 0; ks < 2; ++ks)
        a[m][ks] = *(const short8*)&smem[ab + (((wm * 4 + m) * 2 + ks) << 9) + rdoff];
    #pragma unroll
    for (int n = 0; n < 2; ++n)
      #pragma unroll
      for (int ks = 0; ks < 2; ++ks)
        b0[n][ks] = *(const short8*)&smem[bbb + (((wn * 2 + n) * 2 + ks) << 9) + rdoff];
    if (t + 1 < nk) stageB(0, t + 1, bb ^ 1);
    __builtin_amdgcn_s_setprio(1);
    #pragma unroll
    for (int m = 0; m < 4; ++m)
      #pragma unroll
      for (int n = 0; n < 2; ++n)
        #pragma unroll
        for (int ks = 0; ks < 2; ++ks)
          acc[0][0][m][n] = __builtin_amdgcn_mfma_f32_16x16x32_bf16(a[m][ks], b0[n][ks], acc[0][0][m][n], 0, 0, 0);
    __builtin_amdgcn_s_setprio(0);
    __builtin_amdgcn_s_barrier();

    // p2: read B1 -> b1 (A0 in regs); stage (t+2).A0; MFMA q(0,1)
    #pragma unroll
    for (int n = 0; n < 2; ++n)
      #pragma unroll
      for (int ks = 0; ks < 2; ++ks)
        b1[n][ks] = *(const short8*)&smem[bbb + 8192 + (((wn * 2 + n) * 2 + ks) << 9) + rdoff];
    if (t + 2 < nk) stageA(0, t + 2, bb);
    __builtin_amdgcn_s_setprio(1);
    #pragma unroll
    for (int m = 0; m < 4; ++m)
      #pragma unroll
      for (int n = 0; n < 2; ++n)
        #pragma unroll
        for (int ks = 0; ks < 2; ++ks)
          acc[0][1][m][n] = __builtin_amdgcn_mfma_f32_16x16x32_bf16(a[m][ks], b1[n][ks], acc[0][1][m][n], 0, 0, 0);
    __builtin_amdgcn_s_setprio(0);
    __builtin_amdgcn_s_barrier();

    // p3: read A1 -> a (B1 in regs); stage (t+2).B1; MFMA q(1,1)
    #pragma unroll
    for (int m = 0; m < 4; ++m)
      #pragma unroll
      for (int ks = 0; ks < 2; ++ks)
        a[m][ks] = *(const short8*)&smem[ab + 8192 + (((wm * 4 + m) * 2 + ks) << 9) + rdoff];
    if (t + 2 < nk) stageB(1, t + 2, bb);
    __builtin_amdgcn_s_setprio(1);
    #pragma unroll
    for (int m = 0; m < 4; ++m)
      #pragma unroll
      for (int n = 0; n < 2; ++n)
        #pragma unroll
        for (int ks = 0; ks < 2; ++ks)
          acc[1][1][m][n] = __builtin_amdgcn_mfma_f32_16x16x32_bf16(a[m][ks], b1[n][ks], acc[1][1][m][n], 0, 0, 0);
    __builtin_amdgcn_s_setprio(0);
    __builtin_amdgcn_s_barrier();

    // p4: no reads (a = A1, b0 = B0); stage (t+2).A1; MFMA q(1,0); certify
    if (t + 2 < nk) stageA(1, t + 2, bb);
    __builtin_amdgcn_s_setprio(1);
    #pragma unroll
    for (int m = 0; m < 4; ++m)
      #pragma unroll
      for (int n = 0; n < 2; ++n)
        #pragma unroll
        for (int ks = 0; ks < 2; ++ks)
          acc[1][0][m][n] = __builtin_amdgcn_mfma_f32_16x16x32_bf16(a[m][ks], b0[n][ks], acc[1][0][m][n], 0, 0, 0);
    __builtin_amdgcn_s_setprio(0);
    if (t + 2 < nk) { asm volatile("s_waitcnt vmcnt(6)" ::: "memory"); }
    else            { asm volatile("s_waitcnt vmcnt(0)" ::: "memory"); }
    __builtin_amdgcn_s_barrier();
  }

  const int r0 = bm * 256 + wm * 64 + kg * 4;
  const int c0 = bn * 256 + wn * 32 + lr;
  #pragma unroll
  for (int qa = 0; qa < 2; ++qa) {
    #pragma unroll
    for (int qb = 0; qb < 2; ++qb) {
      #pragma unroll
      for (int n = 0; n < 2; ++n) {
        const int c = c0 + qb * 128 + n * 16;
        const float bv = (EPI >= 1) ? bias[c] : 0.f;
        #pragma unroll
        for (int m = 0; m < 4; ++m) {
          #pragma unroll
          for (int j = 0; j < 4; ++j) {
            const int r = r0 + qa * 128 + m * 16 + j;
            float v = acc[qa][qb][m][n][j];
            if (EPI == 0) {
              Cf[(size_t)r * N + c] = v;
            } else if (EPI == 1) {
              Cb[(size_t)r * N + c] = f2bf(v + bv);
            } else {
              v = fmaxf(v + bv, 0.f) + resid[(size_t)r * N + c];
              Cf[(size_t)r * N + c] = v;
            }
          }
        }
      }
    }
  }
}

// ================= gemm192: C[M,N] = A[M,K] @ B[N,K]^T, 256x192 =================
// 2 phases/K-tile. Per-wave output 128 (x2 qa) x 48 (3 frags).
// Per buffer (56 KiB = 57344 B = 28672 shorts): A0@0, A1@16384B, B@32768B.
template<int EPI>
__global__ __launch_bounds__(512, 2) void gemm192(
    const short* __restrict__ A, const short* __restrict__ Bm,
    int N, int K, int NB,
    float* __restrict__ Cf, short* __restrict__ Cb,
    const float* __restrict__ bias, const float* __restrict__ resid) {
  __shared__ __align__(16) short smem[57344];   // 112 KiB total

  const int tid  = threadIdx.x;
  const int lane = tid & 63;
  const int wid  = tid >> 6;
  const int wm   = wid >> 2;           // 0..1 (64-row half of the 128-row A-half)
  const int wn   = wid & 3;            // 0..3 (48-col strip)
  const int lr   = lane & 15, kg = lane >> 4;

  const int nwg = gridDim.x;
  const int cpx = nwg >> 3;
  const int bid = blockIdx.x;
  const int sw  = (bid & 7) * cpx + (bid >> 3);
  const int bm = sw / NB, bn = sw - bm * NB;

  const int nk = K >> 6;

  const int srl = lane >> 2;
  const int sce = ((lane & 3) << 3) ^ ((lane & 32) ? 16 : 0);

  auto stageA = [&](int h, int kt, int bb) {        // 128x64 half, 2 loads/thread
    const size_t row0 = (size_t)(bm * 256 + h * 128);
    #pragma unroll
    for (int i = 0; i < 2; ++i) {
      const int s = i * 8 + wid;
      const short* src = A + (row0 + (s >> 1) * 16 + srl) * (size_t)K + (kt << 6) + (s & 1) * 32 + sce;
      __builtin_amdgcn_global_load_lds(
        (const __attribute__((address_space(1))) void*)src,
        (__attribute__((address_space(3))) void*)((char*)smem + bb * 57344 + h * 16384 + s * 1024 + lane * 16),
        16, 0, 0);
    }
  };
  auto stageB = [&](int kt, int bb) {               // 192x64, 3 loads/thread
    const size_t row0 = (size_t)(bn * 192);
    #pragma unroll
    for (int i = 0; i < 3; ++i) {
      const int s = i * 8 + wid;
      const short* src = Bm + (row0 + (s >> 1) * 16 + srl) * (size_t)K + (kt << 6) + (s & 1) * 32 + sce;
      __builtin_amdgcn_global_load_lds(
        (const __attribute__((address_space(1))) void*)src,
        (__attribute__((address_space(3))) void*)((char*)smem + bb * 57344 + 32768 + s * 1024 + lane * 16),
        16, 0, 0);
    }
  };

  const int rdoff = lr * 32 + ((kg << 3) ^ ((lr & 8) << 1));

  float4v acc[2][4][3] = {};      // [qa][m][n]
  short8 a[4][2], b[3][2];

  // prologue: t0.{B,A0,A1} + t1.B; certify t0, publish
  stageB(0, 0); stageA(0, 0, 0); stageA(1, 0, 0);
  if (nk > 1) stageB(1, 1);
  asm volatile("s_waitcnt vmcnt(3)" ::: "memory");
  __builtin_amdgcn_s_barrier();

  for (int t = 0; t < nk; ++t) {
    const int bb = t & 1;
    const int ab  = bb * 28672;          // buffer base in SHORTS
    const int bbb = bb * 28672 + 16384;  // B region (byte 32768)

    // p1: read A0 -> a, B -> b; stage (t+1).{A0,A1} -> bb^1; MFMA qa=0
    #pragma unroll
    for (int m = 0; m < 4; ++m)
      #pragma unroll
      for (int ks = 0; ks < 2; ++ks)
        a[m][ks] = *(const short8*)&smem[ab + (((wm * 4 + m) * 2 + ks) << 9) + rdoff];
    #pragma unroll
    for (int n = 0; n < 3; ++n)
      #pragma unroll
      for (int ks = 0; ks < 2; ++ks)
        b[n][ks] = *(const short8*)&smem[bbb + (((wn * 3 + n) * 2 + ks) << 9) + rdoff];
    if (t + 1 < nk) { stageA(0, t + 1, bb ^ 1); stageA(1, t + 1, bb ^ 1); }
    __builtin_amdgcn_s_setprio(1);
    #pragma unroll
    for (int m = 0; m < 4; ++m)
      #pragma unroll
      for (int n = 0; n < 3; ++n)
        #pragma unroll
        for (int ks = 0; ks < 2; ++ks)
          acc[0][m][n] = __builtin_amdgcn_mfma_f32_16x16x32_bf16(a[m][ks], b[n][ks], acc[0][m][n], 0, 0, 0);
    __builtin_amdgcn_s_setprio(0);
    __builtin_amdgcn_s_barrier();

    // p2: read A1 -> a (B in regs); stage (t+2).B -> bb; MFMA qa=1; certify
    #pragma unroll
    for (int m = 0; m < 4; ++m)
      #pragma unroll
      for (int ks = 0; ks < 2; ++ks)
        a[m][ks] = *(const short8*)&smem[ab + 8192 + (((wm * 4 + m) * 2 + ks) << 9) + rdoff];
    if (t + 2 < nk) stageB(t + 2, bb);
    __builtin_amdgcn_s_setprio(1);
    #pragma unroll
    for (int m = 0; m < 4; ++m)
      #pragma unroll
      for (int n = 0; n < 3; ++n)
        #pragma unroll
        for (int ks = 0; ks < 2; ++ks)
          acc[1][m][n] = __builtin_amdgcn_mfma_f32_16x16x32_bf16(a[m][ks], b[n][ks], acc[1][m][n], 0, 0, 0);
    __builtin_amdgcn_s_setprio(0);
    if (t + 2 < nk) { asm volatile("s_waitcnt vmcnt(3)" ::: "memory"); }
    else            { asm volatile("s_waitcnt vmcnt(0)" ::: "memory"); }
    __builtin_amdgcn_s_barrier();
  }

  const int r0 = bm * 256 + wm * 64 + kg * 4;
  const int c0 = bn * 192 + wn * 48 + lr;
  #pragma unroll
  for (int qa = 0; qa < 2; ++qa) {
    #pragma unroll
    for (int n = 0; n < 3; ++n) {
      const int c = c0 + n * 16;
      const float bv = (EPI >= 1) ? bias[c] : 0.f;
      #pragma unroll
      for (int m = 0; m < 4; ++m) {
        #pragma unroll
        for (int j = 0; j < 4; ++j) {
          const int r = r0 + qa * 128 + m * 16 + j;
          float v = acc[qa][m][n][j];
          if (EPI == 0) {
            Cf[(size_t)r * N + c] = v;
          } else if (EPI == 1) {
            Cb[(size_t)r * N + c] = f2bf(v + bv);
          } else {
            v = fmaxf(v + bv, 0.f) + resid[(size_t)r * N + c];
            Cf[(size_t)r * N + c] = v;
          }
        }
      }
    }
  }
}

extern "C" void kernel_launch(void* const* d_in, const int* in_sizes, int n_in,
                              void* d_out, int out_size, void* d_ws, size_t ws_size,
                              hipStream_t stream) {
  const float* x      = (const float*)d_in[0];
  const float* g1     = (const float*)d_in[1];
  const float* b1     = (const float*)d_in[2];
  const float* w_attn = (const float*)d_in[3];
  const float* g2     = (const float*)d_in[4];
  const float* b2     = (const float*)d_in[5];
  const float* w_fc   = (const float*)d_in[6];
  const float* b_fc   = (const float*)d_in[7];
  const float* w_proj = (const float*)d_in[8];
  const float* b_proj = (const float*)d_in[9];
  const int*   mask   = (const int*)d_in[10];
  float* out = (float*)d_out;

  const int S = 4096, E = 768, H = 3072;
  const int M = 4 * S;                 // 16384 rows

  char* p = (char*)d_ws;
  short* hbuf = (short*)p; p += (size_t)M * E * 2;   // h / h2
  float* lgx  = (float*)p; p += (size_t)M * E * 4;   // logits / xres
  short* ubuf = (short*)p; p += (size_t)M * H * 2;   // u bf16
  short* wa   = (short*)p; p += (size_t)E * E * 2;
  short* wf   = (short*)p; p += (size_t)H * E * 2;
  short* wp   = (short*)p; p += (size_t)E * H * 2;

  // 1. weight casts
  cast_bf16_kernel<<<(E*E/4 + 255)/256, 256, 0, stream>>>(w_attn, wa, E*E/4);
  cast_bf16_kernel<<<(H*E/4 + 255)/256, 256, 0, stream>>>(w_fc,   wf, H*E/4);
  cast_bf16_kernel<<<(E*H/4 + 255)/256, 256, 0, stream>>>(w_proj, wp, E*H/4);

  // 2. LN1
  ln_kernel<<<M, 192, 0, stream>>>(x, g1, b1, hbuf);

  // 3. logits = h @ w_attn^T   (grid 64*4 = 256, exact CU cover)
  gemm192<0><<<(M/256) * (E/192), 512, 0, stream>>>(hbuf, wa, E, E, E/192, lgx, nullptr, nullptr, nullptr);

  // 4. masked softmax + residual + LN2
  smres_ln_kernel<<<M, 192, 0, stream>>>(lgx, x, mask, g2, b2, hbuf);

  // 5. u = h2 @ w_fc^T + b_fc  (bf16)   (grid 64*12 = 768)
  gemm256<1><<<(M/256) * (H/256), 512, 0, stream>>>(hbuf, wf, H, E, H/256, nullptr, ubuf, b_fc, nullptr);

  // 6. out = xres + relu(u @ w_proj^T + b_proj)   (grid 64*4 = 256)
  gemm192<2><<<(M/256) * (E/192), 512, 0, stream>>>(ubuf, wp, E, H, E/192, out, nullptr, b_proj, lgx);
}

// Round 6
// 247.555 us; speedup vs baseline: 1.6162x; 1.0061x over previous
//
#include <hip/hip_runtime.h>

// Fused transformer block on MI355X (gfx950).
// Two GEMM templates, both: BK=64, 512 thr = 8 waves, st_16x32-swizzled LDS
// (linear global_load_lds dest + inverse-swizzled global source), single
// barrier per phase (compiler emits counted lgkmcnt between ds_read and MFMA),
// counted vmcnt placed BEFORE the phase-closing barrier (per-wave certify,
// then publish), setprio(1) around MFMA clusters, bm-major XCD swizzle.
//
// gemm256: 256x256 tile, 4 quadrant-phases/K-tile, B0 kept in regs (p4 has
//          zero LDS reads). Stage stream: p1->(t+1).B0, p2->(t+2).A0,
//          p3->(t+2).B1, p4->(t+2).A1; boundary vmcnt(6).
//          LDS 128 KiB: buffer stride 65536 B (32768 shorts).
// gemm192: 256x192 tile (grid = 64*4 = 256 = exact CU cover for N=768),
//          2 phases/K-tile. R5 profile showed A-prefetch slack of only 1
//          phase -> waves stall ~2-3k cyc/tile at the boundary vmcnt.
//          R6: A is a 3-deep ring (t%3, 3x32 KiB); p1(t) stages A(t+2)
//          [region (t+2)%3=(t-1)%3, WAR-safe after t-1's boundary barrier],
//          p2(t) stages B(t+2) (2-buf); boundary vmcnt(7) = A(t+2).4+B(t+2).3.
//          A-slack ~3 phases covers HBM latency. LDS 144 KiB, 1 block/CU.

typedef __attribute__((ext_vector_type(8))) short short8;
typedef __attribute__((ext_vector_type(4))) short short4v;
typedef __attribute__((ext_vector_type(4))) float float4v;
typedef __attribute__((ext_vector_type(4))) int   int4v;

#define LN_EPS 1e-5f

__device__ __forceinline__ short f2bf(float f) {
  unsigned u = __float_as_uint(f);
  unsigned r = (u + 0x7fffu + ((u >> 16) & 1u)) >> 16;
  return (short)r;
}

// ---- block reduces for 192-thread (3-wave) row kernels ----
__device__ __forceinline__ float brsum192(float v, float* red) {
  #pragma unroll
  for (int o = 32; o > 0; o >>= 1) v += __shfl_down(v, o, 64);
  __syncthreads();
  if ((threadIdx.x & 63) == 0) red[threadIdx.x >> 6] = v;
  __syncthreads();
  return red[0] + red[1] + red[2];
}

__device__ __forceinline__ float brmax192(float v, float* red) {
  #pragma unroll
  for (int o = 32; o > 0; o >>= 1) v = fmaxf(v, __shfl_down(v, o, 64));
  __syncthreads();
  if ((threadIdx.x & 63) == 0) red[threadIdx.x >> 6] = v;
  __syncthreads();
  return fmaxf(fmaxf(red[0], red[1]), red[2]);
}

// ---- fp32 -> bf16 cast (weights) ----
__global__ void cast_bf16_kernel(const float* __restrict__ in, short* __restrict__ out, int n4) {
  int i = blockIdx.x * blockDim.x + threadIdx.x;
  if (i >= n4) return;
  float4v v = reinterpret_cast<const float4v*>(in)[i];
  short4v o;
  o.x = f2bf(v.x); o.y = f2bf(v.y); o.z = f2bf(v.z); o.w = f2bf(v.w);
  reinterpret_cast<short4v*>(out)[i] = o;
}

// ---- LN over rows of 768, write bf16 ----
__global__ __launch_bounds__(192) void ln_kernel(const float* __restrict__ x,
    const float* __restrict__ g, const float* __restrict__ b, short* __restrict__ h) {
  __shared__ float red[3];
  const int row = blockIdx.x, tid = threadIdx.x;
  const float4v v = reinterpret_cast<const float4v*>(x + (size_t)row * 768)[tid];
  const float s = brsum192(v.x + v.y + v.z + v.w, red);
  const float mu = s * (1.f / 768.f);
  const float dx = v.x - mu, dy = v.y - mu, dz = v.z - mu, dw = v.w - mu;
  const float sq = brsum192(dx*dx + dy*dy + dz*dz + dw*dw, red);
  const float rs = rsqrtf(sq * (1.f / 768.f) + LN_EPS);
  const float4v gv = reinterpret_cast<const float4v*>(g)[tid];
  const float4v bv = reinterpret_cast<const float4v*>(b)[tid];
  short4v o;
  o.x = f2bf(dx * rs * gv.x + bv.x);
  o.y = f2bf(dy * rs * gv.y + bv.y);
  o.z = f2bf(dz * rs * gv.z + bv.z);
  o.w = f2bf(dw * rs * gv.w + bv.w);
  reinterpret_cast<short4v*>(h + (size_t)row * 768)[tid] = o;
}

// ---- masked softmax + residual + LN2 (+bf16 cast), one row per block ----
__global__ __launch_bounds__(192) void smres_ln_kernel(
    float* __restrict__ lgx, const float* __restrict__ x, const int* __restrict__ mask,
    const float* __restrict__ g, const float* __restrict__ b, short* __restrict__ h2) {
  __shared__ float red[3];
  const int row = blockIdx.x, tid = threadIdx.x;
  const int srow = row & 4095;
  const float4v lg = reinterpret_cast<float4v*>(lgx + (size_t)row * 768)[tid];
  const int4v mk = reinterpret_cast<const int4v*>(mask + (size_t)srow * 768)[tid];
  const float m0 = mk.x ? lg.x : -1e9f;
  const float m1 = mk.y ? lg.y : -1e9f;
  const float m2 = mk.z ? lg.z : -1e9f;
  const float m3 = mk.w ? lg.w : -1e9f;
  const float mx = brmax192(fmaxf(fmaxf(m0, m1), fmaxf(m2, m3)), red);
  const float p0 = __expf(m0 - mx), p1 = __expf(m1 - mx);
  const float p2 = __expf(m2 - mx), p3 = __expf(m3 - mx);
  const float inv = 1.f / brsum192(p0 + p1 + p2 + p3, red);
  const float4v xv = reinterpret_cast<const float4v*>(x + (size_t)row * 768)[tid];
  const float r0 = xv.x + p0 * inv, r1 = xv.y + p1 * inv;
  const float r2 = xv.z + p2 * inv, r3 = xv.w + p3 * inv;
  float4v xr; xr.x = r0; xr.y = r1; xr.z = r2; xr.w = r3;
  reinterpret_cast<float4v*>(lgx + (size_t)row * 768)[tid] = xr;
  const float mu = brsum192(r0 + r1 + r2 + r3, red) * (1.f / 768.f);
  const float d0 = r0 - mu, d1 = r1 - mu, d2 = r2 - mu, d3 = r3 - mu;
  const float var = brsum192(d0*d0 + d1*d1 + d2*d2 + d3*d3, red) * (1.f / 768.f);
  const float rs = rsqrtf(var + LN_EPS);
  const float4v gv = reinterpret_cast<const float4v*>(g)[tid];
  const float4v bv = reinterpret_cast<const float4v*>(b)[tid];
  short4v o;
  o.x = f2bf(d0 * rs * gv.x + bv.x);
  o.y = f2bf(d1 * rs * gv.y + bv.y);
  o.z = f2bf(d2 * rs * gv.z + bv.z);
  o.w = f2bf(d3 * rs * gv.w + bv.w);
  reinterpret_cast<short4v*>(h2 + (size_t)row * 768)[tid] = o;
}

// ================= gemm256: C[M,N] = A[M,K] @ B[N,K]^T, 256x256 =================
template<int EPI>
__global__ __launch_bounds__(512, 2) void gemm256(
    const short* __restrict__ A, const short* __restrict__ Bm,
    int N, int K, int NB,
    float* __restrict__ Cf, short* __restrict__ Cb,
    const float* __restrict__ bias, const float* __restrict__ resid) {
  // 128 KiB LDS: per buffer (64 KiB): A0@0, A1@16K, B0@32K, B1@48K (bytes)
  __shared__ __align__(16) short smem[65536];

  const int tid  = threadIdx.x;
  const int lane = tid & 63;
  const int wid  = tid >> 6;
  const int wm   = wid >> 2;           // 0..1
  const int wn   = wid & 3;            // 0..3
  const int lr   = lane & 15, kg = lane >> 4;

  const int nwg = gridDim.x;
  const int cpx = nwg >> 3;
  const int bid = blockIdx.x;
  const int sw  = (bid & 7) * cpx + (bid >> 3);
  const int bm = sw / NB, bn = sw - bm * NB;

  const int nk = K >> 6;

  const int srl = lane >> 2;
  const int sce = ((lane & 3) << 3) ^ ((lane & 32) ? 16 : 0);

  auto stageA = [&](int h, int kt, int bb) {
    const size_t row0 = (size_t)(bm * 256 + h * 128);
    #pragma unroll
    for (int i = 0; i < 2; ++i) {
      const int s = i * 8 + wid;
      const short* src = A + (row0 + (s >> 1) * 16 + srl) * (size_t)K + (kt << 6) + (s & 1) * 32 + sce;
      __builtin_amdgcn_global_load_lds(
        (const __attribute__((address_space(1))) void*)src,
        (__attribute__((address_space(3))) void*)((char*)smem + bb * 65536 + h * 16384 + s * 1024 + lane * 16),
        16, 0, 0);
    }
  };
  auto stageB = [&](int h, int kt, int bb) {
    const size_t row0 = (size_t)(bn * 256 + h * 128);
    #pragma unroll
    for (int i = 0; i < 2; ++i) {
      const int s = i * 8 + wid;
      const short* src = Bm + (row0 + (s >> 1) * 16 + srl) * (size_t)K + (kt << 6) + (s & 1) * 32 + sce;
      __builtin_amdgcn_global_load_lds(
        (const __attribute__((address_space(1))) void*)src,
        (__attribute__((address_space(3))) void*)((char*)smem + bb * 65536 + 32768 + h * 16384 + s * 1024 + lane * 16),
        16, 0, 0);
    }
  };

  const int rdoff = lr * 32 + ((kg << 3) ^ ((lr & 8) << 1));

  float4v acc[2][2][4][2] = {};   // [qa][qb][m][n]
  short8 a[4][2], b0[2][2], b1[2][2];

  // prologue: t0.{A0,B0,B1,A1} + t1.{A0,B1,A1}; certify t0, publish
  stageA(0, 0, 0); stageB(0, 0, 0); stageB(1, 0, 0); stageA(1, 0, 0);
  if (nk > 1) { stageA(0, 1, 1); stageB(1, 1, 1); stageA(1, 1, 1); }
  asm volatile("s_waitcnt vmcnt(6)" ::: "memory");
  __builtin_amdgcn_s_barrier();

  for (int t = 0; t < nk; ++t) {
    const int bb  = t & 1;
    const int ab  = bb * 32768;
    const int bbb = bb * 32768 + 16384;

    // p1: read A0 -> a, B0 -> b0; stage (t+1).B0; MFMA q(0,0)
    #pragma unroll
    for (int m = 0; m < 4; ++m)
      #pragma unroll
      for (int ks = 0; ks < 2; ++ks)
        a[m][ks] = *(const short8*)&smem[ab + (((wm * 4 + m) * 2 + ks) << 9) + rdoff];
    #pragma unroll
    for (int n = 0; n < 2; ++n)
      #pragma unroll
      for (int ks = 0; ks < 2; ++ks)
        b0[n][ks] = *(const short8*)&smem[bbb + (((wn * 2 + n) * 2 + ks) << 9) + rdoff];
    if (t + 1 < nk) stageB(0, t + 1, bb ^ 1);
    __builtin_amdgcn_s_setprio(1);
    #pragma unroll
    for (int m = 0; m < 4; ++m)
      #pragma unroll
      for (int n = 0; n < 2; ++n)
        #pragma unroll
        for (int ks = 0; ks < 2; ++ks)
          acc[0][0][m][n] = __builtin_amdgcn_mfma_f32_16x16x32_bf16(a[m][ks], b0[n][ks], acc[0][0][m][n], 0, 0, 0);
    __builtin_amdgcn_s_setprio(0);
    __builtin_amdgcn_s_barrier();

    // p2: read B1 -> b1 (A0 in regs); stage (t+2).A0; MFMA q(0,1)
    #pragma unroll
    for (int n = 0; n < 2; ++n)
      #pragma unroll
      for (int ks = 0; ks < 2; ++ks)
        b1[n][ks] = *(const short8*)&smem[bbb + 8192 + (((wn * 2 + n) * 2 + ks) << 9) + rdoff];
    if (t + 2 < nk) stageA(0, t + 2, bb);
    __builtin_amdgcn_s_setprio(1);
    #pragma unroll
    for (int m = 0; m < 4; ++m)
      #pragma unroll
      for (int n = 0; n < 2; ++n)
        #pragma unroll
        for (int ks = 0; ks < 2; ++ks)
          acc[0][1][m][n] = __builtin_amdgcn_mfma_f32_16x16x32_bf16(a[m][ks], b1[n][ks], acc[0][1][m][n], 0, 0, 0);
    __builtin_amdgcn_s_setprio(0);
    __builtin_amdgcn_s_barrier();

    // p3: read A1 -> a (B1 in regs); stage (t+2).B1; MFMA q(1,1)
    #pragma unroll
    for (int m = 0; m < 4; ++m)
      #pragma unroll
      for (int ks = 0; ks < 2; ++ks)
        a[m][ks] = *(const short8*)&smem[ab + 8192 + (((wm * 4 + m) * 2 + ks) << 9) + rdoff];
    if (t + 2 < nk) stageB(1, t + 2, bb);
    __builtin_amdgcn_s_setprio(1);
    #pragma unroll
    for (int m = 0; m < 4; ++m)
      #pragma unroll
      for (int n = 0; n < 2; ++n)
        #pragma unroll
        for (int ks = 0; ks < 2; ++ks)
          acc[1][1][m][n] = __builtin_amdgcn_mfma_f32_16x16x32_bf16(a[m][ks], b1[n][ks], acc[1][1][m][n], 0, 0, 0);
    __builtin_amdgcn_s_setprio(0);
    __builtin_amdgcn_s_barrier();

    // p4: no reads (a = A1, b0 = B0); stage (t+2).A1; MFMA q(1,0); certify
    if (t + 2 < nk) stageA(1, t + 2, bb);
    __builtin_amdgcn_s_setprio(1);
    #pragma unroll
    for (int m = 0; m < 4; ++m)
      #pragma unroll
      for (int n = 0; n < 2; ++n)
        #pragma unroll
        for (int ks = 0; ks < 2; ++ks)
          acc[1][0][m][n] = __builtin_amdgcn_mfma_f32_16x16x32_bf16(a[m][ks], b0[n][ks], acc[1][0][m][n], 0, 0, 0);
    __builtin_amdgcn_s_setprio(0);
    if (t + 2 < nk) { asm volatile("s_waitcnt vmcnt(6)" ::: "memory"); }
    else            { asm volatile("s_waitcnt vmcnt(0)" ::: "memory"); }
    __builtin_amdgcn_s_barrier();
  }

  const int r0 = bm * 256 + wm * 64 + kg * 4;
  const int c0 = bn * 256 + wn * 32 + lr;
  #pragma unroll
  for (int qa = 0; qa < 2; ++qa) {
    #pragma unroll
    for (int qb = 0; qb < 2; ++qb) {
      #pragma unroll
      for (int n = 0; n < 2; ++n) {
        const int c = c0 + qb * 128 + n * 16;
        const float bv = (EPI >= 1) ? bias[c] : 0.f;
        #pragma unroll
        for (int m = 0; m < 4; ++m) {
          #pragma unroll
          for (int j = 0; j < 4; ++j) {
            const int r = r0 + qa * 128 + m * 16 + j;
            float v = acc[qa][qb][m][n][j];
            if (EPI == 0) {
              Cf[(size_t)r * N + c] = v;
            } else if (EPI == 1) {
              Cb[(size_t)r * N + c] = f2bf(v + bv);
            } else {
              v = fmaxf(v + bv, 0.f) + resid[(size_t)r * N + c];
              Cf[(size_t)r * N + c] = v;
            }
          }
        }
      }
    }
  }
}

// ================= gemm192: C[M,N] = A[M,K] @ B[N,K]^T, 256x192 =================
// 2 phases/K-tile. Per-wave output 128 (x2 qa) x 48 (3 frags).
// LDS 144 KiB: A ring x3 (t%3) @ r*32768 B {A0@+0, A1@+16384}, B x2 @ 98304
// + bb*24576 B. p1(t) stages A(t+2); p2(t) stages B(t+2); boundary vmcnt(7).
template<int EPI>
__global__ __launch_bounds__(512, 2) void gemm192(
    const short* __restrict__ A, const short* __restrict__ Bm,
    int N, int K, int NB,
    float* __restrict__ Cf, short* __restrict__ Cb,
    const float* __restrict__ bias, const float* __restrict__ resid) {
  __shared__ __align__(16) short smem[73728];   // 147456 B = 144 KiB

  const int tid  = threadIdx.x;
  const int lane = tid & 63;
  const int wid  = tid >> 6;
  const int wm   = wid >> 2;           // 0..1 (64-row half of the 128-row A-half)
  const int wn   = wid & 3;            // 0..3 (48-col strip)
  const int lr   = lane & 15, kg = lane >> 4;

  const int nwg = gridDim.x;
  const int cpx = nwg >> 3;
  const int bid = blockIdx.x;
  const int sw  = (bid & 7) * cpx + (bid >> 3);
  const int bm = sw / NB, bn = sw - bm * NB;

  const int nk = K >> 6;

  const int srl = lane >> 2;
  const int sce = ((lane & 3) << 3) ^ ((lane & 32) ? 16 : 0);

  auto stageA = [&](int h, int kt, int r) {         // 128x64 half, 2 loads/thread
    const size_t row0 = (size_t)(bm * 256 + h * 128);
    #pragma unroll
    for (int i = 0; i < 2; ++i) {
      const int s = i * 8 + wid;
      const short* src = A + (row0 + (s >> 1) * 16 + srl) * (size_t)K + (kt << 6) + (s & 1) * 32 + sce;
      __builtin_amdgcn_global_load_lds(
        (const __attribute__((address_space(1))) void*)src,
        (__attribute__((address_space(3))) void*)((char*)smem + r * 32768 + h * 16384 + s * 1024 + lane * 16),
        16, 0, 0);
    }
  };
  auto stageB = [&](int kt, int bb) {               // 192x64, 3 loads/thread
    const size_t row0 = (size_t)(bn * 192);
    #pragma unroll
    for (int i = 0; i < 3; ++i) {
      const int s = i * 8 + wid;
      const short* src = Bm + (row0 + (s >> 1) * 16 + srl) * (size_t)K + (kt << 6) + (s & 1) * 32 + sce;
      __builtin_amdgcn_global_load_lds(
        (const __attribute__((address_space(1))) void*)src,
        (__attribute__((address_space(3))) void*)((char*)smem + 98304 + bb * 24576 + s * 1024 + lane * 16),
        16, 0, 0);
    }
  };

  const int rdoff = lr * 32 + ((kg << 3) ^ ((lr & 8) << 1));

  float4v acc[2][4][3] = {};      // [qa][m][n]
  short8 a[4][2], b[3][2];

  // prologue: stage A(0),B(0) then A(1),B(1); certify tile 0 (7 loads), publish
  stageA(0, 0, 0); stageB(0, 0); stageA(1, 0, 0);
  if (nk > 1) { stageA(0, 1, 1); stageB(1, 1); stageA(1, 1, 1); }
  asm volatile("s_waitcnt vmcnt(7)" ::: "memory");
  __builtin_amdgcn_s_barrier();

  int ar = 0, ar2 = 2;            // t%3, (t+2)%3
  for (int t = 0; t < nk; ++t) {
    const int bb   = t & 1;
    const int ab   = ar * 16384;          // A ring base in SHORTS
    const int bbb  = 49152 + bb * 12288;  // B base in SHORTS (byte 98304)

    // p1: read A0 -> a, B -> b; stage A(t+2) -> ring ar2; MFMA qa=0
    #pragma unroll
    for (int m = 0; m < 4; ++m)
      #pragma unroll
      for (int ks = 0; ks < 2; ++ks)
        a[m][ks] = *(const short8*)&smem[ab + (((wm * 4 + m) * 2 + ks) << 9) + rdoff];
    #pragma unroll
    for (int n = 0; n < 3; ++n)
      #pragma unroll
      for (int ks = 0; ks < 2; ++ks)
        b[n][ks] = *(const short8*)&smem[bbb + (((wn * 3 + n) * 2 + ks) << 9) + rdoff];
    if (t + 2 < nk) { stageA(0, t + 2, ar2); stageA(1, t + 2, ar2); }
    __builtin_amdgcn_s_setprio(1);
    #pragma unroll
    for (int m = 0; m < 4; ++m)
      #pragma unroll
      for (int n = 0; n < 3; ++n)
        #pragma unroll
        for (int ks = 0; ks < 2; ++ks)
          acc[0][m][n] = __builtin_amdgcn_mfma_f32_16x16x32_bf16(a[m][ks], b[n][ks], acc[0][m][n], 0, 0, 0);
    __builtin_amdgcn_s_setprio(0);
    __builtin_amdgcn_s_barrier();

    // p2: read A1 -> a (B in regs); stage B(t+2) -> bb; MFMA qa=1; certify
    #pragma unroll
    for (int m = 0; m < 4; ++m)
      #pragma unroll
      for (int ks = 0; ks < 2; ++ks)
        a[m][ks] = *(const short8*)&smem[ab + 8192 + (((wm * 4 + m) * 2 + ks) << 9) + rdoff];
    if (t + 2 < nk) stageB(t + 2, bb);
    __builtin_amdgcn_s_setprio(1);
    #pragma unroll
    for (int m = 0; m < 4; ++m)
      #pragma unroll
      for (int n = 0; n < 3; ++n)
        #pragma unroll
        for (int ks = 0; ks < 2; ++ks)
          acc[1][m][n] = __builtin_amdgcn_mfma_f32_16x16x32_bf16(a[m][ks], b[n][ks], acc[1][m][n], 0, 0, 0);
    __builtin_amdgcn_s_setprio(0);
    if (t + 2 < nk) { asm volatile("s_waitcnt vmcnt(7)" ::: "memory"); }
    else            { asm volatile("s_waitcnt vmcnt(0)" ::: "memory"); }
    __builtin_amdgcn_s_barrier();

    ar  = (ar  == 2) ? 0 : ar  + 1;
    ar2 = (ar2 == 2) ? 0 : ar2 + 1;
  }

  const int r0 = bm * 256 + wm * 64 + kg * 4;
  const int c0 = bn * 192 + wn * 48 + lr;
  #pragma unroll
  for (int qa = 0; qa < 2; ++qa) {
    #pragma unroll
    for (int n = 0; n < 3; ++n) {
      const int c = c0 + n * 16;
      const float bv = (EPI >= 1) ? bias[c] : 0.f;
      #pragma unroll
      for (int m = 0; m < 4; ++m) {
        #pragma unroll
        for (int j = 0; j < 4; ++j) {
          const int r = r0 + qa * 128 + m * 16 + j;
          float v = acc[qa][m][n][j];
          if (EPI == 0) {
            Cf[(size_t)r * N + c] = v;
          } else if (EPI == 1) {
            Cb[(size_t)r * N + c] = f2bf(v + bv);
          } else {
            v = fmaxf(v + bv, 0.f) + resid[(size_t)r * N + c];
            Cf[(size_t)r * N + c] = v;
          }
        }
      }
    }
  }
}

extern "C" void kernel_launch(void* const* d_in, const int* in_sizes, int n_in,
                              void* d_out, int out_size, void* d_ws, size_t ws_size,
                              hipStream_t stream) {
  const float* x      = (const float*)d_in[0];
  const float* g1     = (const float*)d_in[1];
  const float* b1     = (const float*)d_in[2];
  const float* w_attn = (const float*)d_in[3];
  const float* g2     = (const float*)d_in[4];
  const float* b2     = (const float*)d_in[5];
  const float* w_fc   = (const float*)d_in[6];
  const float* b_fc   = (const float*)d_in[7];
  const float* w_proj = (const float*)d_in[8];
  const float* b_proj = (const float*)d_in[9];
  const int*   mask   = (const int*)d_in[10];
  float* out = (float*)d_out;

  const int S = 4096, E = 768, H = 3072;
  const int M = 4 * S;                 // 16384 rows

  char* p = (char*)d_ws;
  short* hbuf = (short*)p; p += (size_t)M * E * 2;   // h / h2
  float* lgx  = (float*)p; p += (size_t)M * E * 4;   // logits / xres
  short* ubuf = (short*)p; p += (size_t)M * H * 2;   // u bf16
  short* wa   = (short*)p; p += (size_t)E * E * 2;
  short* wf   = (short*)p; p += (size_t)H * E * 2;
  short* wp   = (short*)p; p += (size_t)E * H * 2;

  // 1. weight casts
  cast_bf16_kernel<<<(E*E/4 + 255)/256, 256, 0, stream>>>(w_attn, wa, E*E/4);
  cast_bf16_kernel<<<(H*E/4 + 255)/256, 256, 0, stream>>>(w_fc,   wf, H*E/4);
  cast_bf16_kernel<<<(E*H/4 + 255)/256, 256, 0, stream>>>(w_proj, wp, E*H/4);

  // 2. LN1
  ln_kernel<<<M, 192, 0, stream>>>(x, g1, b1, hbuf);

  // 3. logits = h @ w_attn^T   (grid 64*4 = 256, exact CU cover)
  gemm192<0><<<(M/256) * (E/192), 512, 0, stream>>>(hbuf, wa, E, E, E/192, lgx, nullptr, nullptr, nullptr);

  // 4. masked softmax + residual + LN2
  smres_ln_kernel<<<M, 192, 0, stream>>>(lgx, x, mask, g2, b2, hbuf);

  // 5. u = h2 @ w_fc^T + b_fc  (bf16)   (grid 64*12 = 768)
  gemm256<1><<<(M/256) * (H/256), 512, 0, stream>>>(hbuf, wf, H, E, H/256, nullptr, ubuf, b_fc, nullptr);

  // 6. out = xres + relu(u @ w_proj^T + b_proj)   (grid 64*4 = 256)
  gemm192<2><<<(M/256) * (E/192), 512, 0, stream>>>(ubuf, wp, E, H, E/192, out, nullptr, b_proj, lgx);
}